// Round 7
// baseline (479.076 us; speedup 1.0000x reference)
//
#include <hip/hip_runtime.h>

typedef __attribute__((ext_vector_type(4))) float f32x4;
typedef __attribute__((ext_vector_type(8))) __bf16 bf16x8;
typedef __attribute__((ext_vector_type(4))) float f32x4v;

#define BK 64
#define TOTALW 4096
#define NROW 32768
static const size_t NXE = 134217728ull;          // NROW*TOTALW
static const size_t WTOT = 2752512ull;           // sum w^2

__device__ __forceinline__ bf16x8 cvt8(f32x4 a, f32x4 b) {
  bf16x8 r;
  r[0] = (__bf16)a.x; r[1] = (__bf16)a.y; r[2] = (__bf16)a.z; r[3] = (__bf16)a.w;
  r[4] = (__bf16)b.x; r[5] = (__bf16)b.y; r[6] = (__bf16)b.z; r[7] = (__bf16)b.w;
  return r;
}

// ---------------- pass 1: fp32 -> bf16 convert of x and all W into ws ----------------
struct CArgs { const float* x; const float* W[8]; ushort* ws; };

__global__ __launch_bounds__(256) void convert_kernel(CArgs a) {
  const size_t tot8 = (NXE + WTOT) >> 3;
  const size_t stride = (size_t)gridDim.x * blockDim.x;
  for (size_t i = (size_t)blockIdx.x * blockDim.x + threadIdx.x; i < tot8; i += stride) {
    const size_t e = i << 3;
    const float* src;
    if (e < NXE) {
      src = a.x + e;
    } else {
      const size_t ew = e - NXE;
      int l = 0; size_t base = 0;
      if (ew >= 16384)   { l = 1; base = 16384; }
      if (ew >= 32768)   { l = 2; base = 32768; }
      if (ew >= 180224)  { l = 3; base = 180224; }
      if (ew >= 327680)  { l = 4; base = 327680; }
      if (ew >= 737280)  { l = 5; base = 737280; }
      if (ew >= 1146880) { l = 6; base = 1146880; }
      if (ew >= 1949696) { l = 7; base = 1949696; }
      const float* w = a.W[0];
      if (l == 1) w = a.W[1]; if (l == 2) w = a.W[2]; if (l == 3) w = a.W[3];
      if (l == 4) w = a.W[4]; if (l == 5) w = a.W[5]; if (l == 6) w = a.W[6];
      if (l == 7) w = a.W[7];
      src = w + (ew - base);
    }
    f32x4 v0 = *(const f32x4*)src;
    f32x4 v1 = *(const f32x4*)(src + 4);
    *(bf16x8*)(a.ws + e) = cvt8(v0, v1);
  }
}

// ---------------- pass 2: bf16 block-diagonal GEMM, 128x256 tile, m97 structure ----------------
// 512 threads, 8 waves. Main path: 2x4 wave grid of 64x64 wave tiles over a
// 128x256 output tile (halves x panel re-reads vs 128-wide tiles: 168->100
// panel-units). Tail path (last 128-wide tile of each odd-nirr block): 4x2
// wave grid of 32x64. Single-buffered LDS (48KB -> LDS allows 3 blocks/CU;
// VGPR<=128 via launch_bounds gives 2 blocks/CU = 16 waves/CU).
struct GArgs { const ushort* xb; const ushort* Wb[8]; float* out; };

__device__ __forceinline__ void gl16(const ushort* g, ushort* l) {
  __builtin_amdgcn_global_load_lds(
      (const __attribute__((address_space(1))) void*)g,
      (__attribute__((address_space(3))) void*)l, 16, 0, 0);
}

__global__ __launch_bounds__(512, 4) void gemm_kernel(GArgs args) {
  __shared__ __align__(16) ushort As[128 * BK];   // 16 KB
  __shared__ __align__(16) ushort Bs[256 * BK];   // 32 KB

  const int tid = threadIdx.x;
  const int bid = blockIdx.x;
  // XCD-aware bijective swizzle: 5120 blocks, 640 per XCD (32 mt x 20 tiles)
  const int work = (bid & 7) * 640 + (bid >> 3);
  const int mt = work / 20;
  // heavy-first within each m-tile: t=19 (l7) down to t=0 (l0)
  const int t  = 19 - (work - mt * 20);

  // t -> (l, j): per-l 256-wide tile counts {1,1,2,2,3,3,4,4}, last tile of
  // each l is 128 wide (nirr odd). tstart(l) = (p+q)(p+1).
  const int l = (t >= 1) + (t >= 2) + (t >= 4) + (t >= 6) + (t >= 9) + (t >= 12) + (t >= 16);
  const int p = l >> 1, q = l & 1;
  const int nirr = l | 1;                      // {1,1,3,3,5,5,7,7}
  const int cstart = 2 * p * p + q * nirr;
  const int w  = nirr << 7;                    // K for this block
  const int nk = nirr << 1;                    // K-steps (BK=64)
  const int sK = cstart << 7;                  // x/out col start of block l
  const int tstart = (p + q) * (p + 1);
  const int j = t - tstart;                    // tile index within l
  const bool tail = (j == p);                  // last tile: 128 wide
  const int col  = sK + j * 256;               // output col base of this tile
  const int noff = j * 256;                    // W_l row offset
  const ushort* __restrict__ Wbl = args.Wb[l];

  // staging: LINEAR lds dest (wave-uniform base + lane*16B); source chunk
  // XOR-permuted so the linear write yields the swizzled layout (rule 21)
  const int trow = tid >> 3;                   // 0..63
  const int schunk = (tid & 7) ^ (trow & 7);
  const ushort* aSrc = args.xb + (size_t)(mt * 128 + trow) * TOTALW + sK + schunk * 8;
  const ushort* bSrc = Wbl + (size_t)(noff + trow) * w + schunk * 8;

  const int lane = tid & 63;
  const int wid  = tid >> 6;                   // 0..7
  const int fr = lane & 15;
  const int kq = lane >> 4;

  if (!tail) {
    // ---- 128x256 tile: wave grid 2x4, wave tile 64x64 ----
    const int wr = (wid >> 2) << 6;
    const int wc = (wid & 3) << 6;
    f32x4v acc[4][4] = {};

    for (int kt = 0; kt < nk; ++kt) {
#pragma unroll
      for (int r = 0; r < 2; ++r)
        gl16(aSrc + (size_t)(r * 64) * TOTALW + kt * 64, &As[r * 4096 + tid * 8]);
#pragma unroll
      for (int r = 0; r < 4; ++r)
        gl16(bSrc + (size_t)(r * 64) * w + kt * 64, &Bs[r * 4096 + tid * 8]);

      asm volatile("s_waitcnt vmcnt(0)" ::: "memory");
      __syncthreads();

#pragma unroll
      for (int kk = 0; kk < 2; ++kk) {
        const int kb = kk * 32 + kq * 8;
        bf16x8 afr[4], bfr[4];
#pragma unroll
        for (int i = 0; i < 4; ++i) {
          const int ra = wr + i * 16 + fr;
          afr[i] = *(const bf16x8*)&As[(ra * BK + kb) ^ ((fr & 7) << 3)];
          const int rb = wc + i * 16 + fr;
          bfr[i] = *(const bf16x8*)&Bs[(rb * BK + kb) ^ ((fr & 7) << 3)];
        }
#pragma unroll
        for (int mi = 0; mi < 4; ++mi)
#pragma unroll
          for (int ni = 0; ni < 4; ++ni)
            acc[mi][ni] = __builtin_amdgcn_mfma_f32_16x16x32_bf16(afr[mi], bfr[ni], acc[mi][ni], 0, 0, 0);
      }
      if (kt + 1 < nk) __syncthreads();
    }

    float* op = args.out + (size_t)(mt * 128 + wr + kq * 4) * TOTALW + col + wc + fr;
#pragma unroll
    for (int mi = 0; mi < 4; ++mi) {
#pragma unroll
      for (int ni = 0; ni < 4; ++ni) {
        float* pp = op + (size_t)(mi * 16) * TOTALW + ni * 16;
        pp[0 * TOTALW] = acc[mi][ni][0];
        pp[1 * TOTALW] = acc[mi][ni][1];
        pp[2 * TOTALW] = acc[mi][ni][2];
        pp[3 * TOTALW] = acc[mi][ni][3];
      }
    }
  } else {
    // ---- 128x128 tail tile: wave grid 4x2, wave tile 32x64 ----
    const int wr = (wid >> 1) << 5;
    const int wc = (wid & 1) << 6;
    f32x4v acc[2][4] = {};

    for (int kt = 0; kt < nk; ++kt) {
#pragma unroll
      for (int r = 0; r < 2; ++r)
        gl16(aSrc + (size_t)(r * 64) * TOTALW + kt * 64, &As[r * 4096 + tid * 8]);
#pragma unroll
      for (int r = 0; r < 2; ++r)
        gl16(bSrc + (size_t)(r * 64) * w + kt * 64, &Bs[r * 4096 + tid * 8]);

      asm volatile("s_waitcnt vmcnt(0)" ::: "memory");
      __syncthreads();

#pragma unroll
      for (int kk = 0; kk < 2; ++kk) {
        const int kb = kk * 32 + kq * 8;
        bf16x8 afr[2], bfr[4];
#pragma unroll
        for (int i = 0; i < 2; ++i) {
          const int ra = wr + i * 16 + fr;
          afr[i] = *(const bf16x8*)&As[(ra * BK + kb) ^ ((fr & 7) << 3)];
        }
#pragma unroll
        for (int i = 0; i < 4; ++i) {
          const int rb = wc + i * 16 + fr;
          bfr[i] = *(const bf16x8*)&Bs[(rb * BK + kb) ^ ((fr & 7) << 3)];
        }
#pragma unroll
        for (int mi = 0; mi < 2; ++mi)
#pragma unroll
          for (int ni = 0; ni < 4; ++ni)
            acc[mi][ni] = __builtin_amdgcn_mfma_f32_16x16x32_bf16(afr[mi], bfr[ni], acc[mi][ni], 0, 0, 0);
      }
      if (kt + 1 < nk) __syncthreads();
    }

    float* op = args.out + (size_t)(mt * 128 + wr + kq * 4) * TOTALW + col + wc + fr;
#pragma unroll
    for (int mi = 0; mi < 2; ++mi) {
#pragma unroll
      for (int ni = 0; ni < 4; ++ni) {
        float* pp = op + (size_t)(mi * 16) * TOTALW + ni * 16;
        pp[0 * TOTALW] = acc[mi][ni][0];
        pp[1 * TOTALW] = acc[mi][ni][1];
        pp[2 * TOTALW] = acc[mi][ni][2];
        pp[3 * TOTALW] = acc[mi][ni][3];
      }
    }
  }
}

// ---------------- fallback (round-1 kernel, used only if ws too small) ----------------
struct FArgs { const float* x; const float* W[8]; float* out; };

__global__ __launch_bounds__(256, 2) void ielin_fb(FArgs args) {
  __shared__ __align__(16) ushort As[128 * BK];
  __shared__ __align__(16) ushort Bs[128 * BK];
  const int tid = threadIdx.x;
  const int bid = blockIdx.x;
  const int work = (bid & 7) * 1024 + (bid >> 3);
  const int mt = work >> 5;
  const int c  = work & 31;
  const int l = (c >= 1) + (c >= 2) + (c >= 5) + (c >= 8) + (c >= 13) + (c >= 18) + (c >= 25);
  const int pp = l >> 1, qq = l & 1;
  const int nirr = l | 1;
  const int cstart = 2 * pp * pp + qq * nirr;
  const int w  = nirr << 7;
  const int sK = cstart << 7;
  const int noff = (c - cstart) << 7;
  const float* __restrict__ Wl = args.W[l];
  const int srow = tid >> 3;
  const int sk   = (tid & 7) << 3;
  const float* ap = args.x + (size_t)(mt * 128 + srow) * TOTALW + sK + sk;
  const float* bp = Wl + (size_t)(noff + srow) * w + sk;
  const size_t aStep = (size_t)32 * TOTALW;
  const size_t bStep = (size_t)32 * w;
  const int lane = tid & 63;
  const int wid  = tid >> 6;
  const int wr = (wid >> 1) << 6;
  const int wc = (wid & 1) << 6;
  const int fr = lane & 15;
  const int kq = lane >> 4;
  f32x4v acc[4][4] = {};
  f32x4 av[4][2], bv[4][2];
  const int nk = w >> 6;
  {
    const float* a = ap; const float* b = bp;
#pragma unroll
    for (int i = 0; i < 4; ++i) {
      av[i][0] = *(const f32x4*)(a); av[i][1] = *(const f32x4*)(a + 4); a += aStep;
      bv[i][0] = *(const f32x4*)(b); bv[i][1] = *(const f32x4*)(b + 4); b += bStep;
    }
  }
  for (int kt = 0; kt < nk; ++kt) {
#pragma unroll
    for (int i = 0; i < 4; ++i) {
      const int row = srow + 32 * i;
      const int e = (row * BK + sk) ^ ((row & 7) << 3);
      *(bf16x8*)&As[e] = cvt8(av[i][0], av[i][1]);
      *(bf16x8*)&Bs[e] = cvt8(bv[i][0], bv[i][1]);
    }
    __syncthreads();
    if (kt + 1 < nk) {
      const float* a = ap + (kt + 1) * BK;
      const float* b = bp + (kt + 1) * BK;
#pragma unroll
      for (int i = 0; i < 4; ++i) {
        av[i][0] = *(const f32x4*)(a); av[i][1] = *(const f32x4*)(a + 4); a += aStep;
        bv[i][0] = *(const f32x4*)(b); bv[i][1] = *(const f32x4*)(b + 4); b += bStep;
      }
    }
#pragma unroll
    for (int kk = 0; kk < 2; ++kk) {
      const int kb = kk * 32 + kq * 8;
      bf16x8 afr[4], bfr[4];
#pragma unroll
      for (int i = 0; i < 4; ++i) {
        const int ra = wr + i * 16 + fr;
        afr[i] = *(const bf16x8*)&As[(ra * BK + kb) ^ ((fr & 7) << 3)];
        const int rb = wc + i * 16 + fr;
        bfr[i] = *(const bf16x8*)&Bs[(rb * BK + kb) ^ ((fr & 7) << 3)];
      }
#pragma unroll
      for (int mi = 0; mi < 4; ++mi)
#pragma unroll
        for (int ni = 0; ni < 4; ++ni)
          acc[mi][ni] = __builtin_amdgcn_mfma_f32_16x16x32_bf16(afr[mi], bfr[ni], acc[mi][ni], 0, 0, 0);
    }
    __syncthreads();
  }
  float* op = args.out + (size_t)(mt * 128 + wr + kq * 4) * TOTALW + (c << 7) + wc + fr;
#pragma unroll
  for (int mi = 0; mi < 4; ++mi) {
#pragma unroll
    for (int ni = 0; ni < 4; ++ni) {
      float* pp = op + (size_t)(mi * 16) * TOTALW + ni * 16;
      pp[0 * TOTALW] = acc[mi][ni][0];
      pp[1 * TOTALW] = acc[mi][ni][1];
      pp[2 * TOTALW] = acc[mi][ni][2];
      pp[3 * TOTALW] = acc[mi][ni][3];
    }
  }
}

extern "C" void kernel_launch(void* const* d_in, const int* in_sizes, int n_in,
                              void* d_out, int out_size, void* d_ws, size_t ws_size,
                              hipStream_t stream) {
  const size_t need = (NXE + WTOT) * 2;
  if (ws_size >= need) {
    CArgs ca;
    ca.x = (const float*)d_in[0];
    for (int i = 0; i < 8; ++i) ca.W[i] = (const float*)d_in[1 + i];
    ca.ws = (ushort*)d_ws;
    convert_kernel<<<4096, 256, 0, stream>>>(ca);

    GArgs ga;
    ga.xb = (const ushort*)d_ws;
    static const size_t cumW[8] = {0, 16384, 32768, 180224, 327680, 737280, 1146880, 1949696};
    for (int i = 0; i < 8; ++i) ga.Wb[i] = (const ushort*)d_ws + NXE + cumW[i];
    ga.out = (float*)d_out;
    gemm_kernel<<<5120, 512, 0, stream>>>(ga);
  } else {
    FArgs fa;
    fa.x = (const float*)d_in[0];
    for (int i = 0; i < 8; ++i) fa.W[i] = (const float*)d_in[1 + i];
    fa.out = (float*)d_out;
    ielin_fb<<<8192, 256, 0, stream>>>(fa);
  }
}